// Round 2
// baseline (162.044 us; speedup 1.0000x reference)
//
#include <hip/hip_runtime.h>

// ---------- complex helpers ----------
__device__ __forceinline__ float2 cmul(float2 a, float2 b) {
    return make_float2(a.x*b.x - a.y*b.y, a.x*b.y + a.y*b.x);
}
__device__ __forceinline__ float2 cfma(float2 a, float2 b, float2 acc) {
    acc.x = fmaf(a.x, b.x, fmaf(-a.y, b.y, acc.x));
    acc.y = fmaf(a.x, b.y, fmaf( a.y, b.x, acc.y));
    return acc;
}
// acc += conj(a) * b
__device__ __forceinline__ float2 cfma_conj(float2 a, float2 b, float2 acc) {
    acc.x = fmaf(a.x, b.x, fmaf( a.y, b.y, acc.x));
    acc.y = fmaf(a.x, b.y, fmaf(-a.y, b.x, acc.y));
    return acc;
}

// ---------- kernel 1: build G = Mq^dagger * Mk (16x16 complex) ----------
// Launch with exactly 16 threads (one partially-filled wave; fine).
// Thread t owns column t of Mq and Mk (16 complex amplitudes each, in regs).
__global__ void qdp_setup(const float* __restrict__ Wq,
                          const float* __restrict__ Wk,
                          float2* __restrict__ G) {
    const int t = threadIdx.x;            // 0..15 = column index
    float2 cq[16], ck[16];
    #pragma unroll
    for (int x = 0; x < 16; ++x) {
        cq[x] = make_float2(x == t ? 1.0f : 0.0f, 0.0f);
        ck[x] = cq[x];
    }

    #pragma unroll
    for (int layer = 0; layer < 2; ++layer) {
        #pragma unroll
        for (int w = 0; w < 4; ++w) {
            const int mask = 1 << (3 - w);          // wire w <-> bit (3-w)
            #pragma unroll
            for (int which = 0; which < 2; ++which) {
                const float* wp = (which ? Wk : Wq) + layer*12 + w*3;
                float2* col = which ? ck : cq;
                const float phi = wp[0], th = wp[1], om = wp[2];
                float c, s;   sincosf(0.5f*th, &s, &c);
                float sap, cap; sincosf(0.5f*(phi+om), &sap, &cap);
                float sam, cam; sincosf(0.5f*(phi-om), &sam, &cam);
                const float2 u00 = make_float2( c*cap, -c*sap);
                const float2 u01 = make_float2(-s*cam, -s*sam);
                const float2 u10 = make_float2( s*cam, -s*sam);
                const float2 u11 = make_float2( c*cap,  c*sap);
                #pragma unroll
                for (int x = 0; x < 16; ++x) {
                    if (x & mask) continue;
                    const int y = x | mask;
                    const float2 a = col[x], b = col[y];
                    float2 nx = cmul(u00, a); nx = cfma(u01, b, nx);
                    float2 ny = cmul(u10, a); ny = cfma(u11, b, ny);
                    col[x] = nx; col[y] = ny;
                }
            }
        }
        #pragma unroll
        for (int w = 0; w < 3; ++w) {               // CNOT(w, w+1)
            const int mc = 1 << (3 - w);            // control bit
            const int mt = 1 << (2 - w);            // target bit
            #pragma unroll
            for (int x = 0; x < 16; ++x) {
                if ((x & mc) && !(x & mt)) {
                    const int y = x | mt;
                    float2 tmp = cq[x]; cq[x] = cq[y]; cq[y] = tmp;
                    tmp = ck[x]; ck[x] = ck[y]; ck[y] = tmp;
                }
            }
        }
    }

    __shared__ float2 MqL[16][16];                  // [row][col]
    #pragma unroll
    for (int kx = 0; kx < 16; ++kx) MqL[kx][t] = cq[kx];
    __syncthreads();

    // G[i][t] = sum_k conj(Mq[k][i]) * Mk[k][t]
    #pragma unroll
    for (int i = 0; i < 16; ++i) {
        float2 acc = make_float2(0.0f, 0.0f);
        #pragma unroll
        for (int kx = 0; kx < 16; ++kx)
            acc = cfma_conj(MqL[kx][i], ck[kx], acc);
        G[i*16 + t] = acc;
    }
}

// ---------- kernel 2: per-element bilinear form ----------
__device__ __forceinline__ float fast_tanh(float x) {
    const float e = __expf(2.0f * x);
    return 1.0f - 2.0f / (e + 1.0f);
}

__global__ __launch_bounds__(256)
void qdp_main(const float* __restrict__ Q, const float* __restrict__ K,
              const float2* __restrict__ G, float* __restrict__ out, int B) {
    __shared__ float2 Gs[256];
    Gs[threadIdx.x] = G[threadIdx.x];               // 256 threads, 256 entries
    __syncthreads();

    const int b = blockIdx.x * 256 + threadIdx.x;
    if (b >= B) return;

    const float4 qv = *reinterpret_cast<const float4*>(Q + (size_t)b * 64);
    const float4 kv = *reinterpret_cast<const float4*>(K + (size_t)b * 64);

    float cq[4], sq[4], ckv[4], skv[4];
    {
        const float qa[4] = {qv.x, qv.y, qv.z, qv.w};
        const float ka[4] = {kv.x, kv.y, kv.z, kv.w};
        #pragma unroll
        for (int i = 0; i < 4; ++i) {
            const float tq = fast_tanh(qa[i]) * 1.57079632679489662f;
            const float tk = fast_tanh(ka[i]) * 1.57079632679489662f;
            __sincosf(tq, &sq[i], &cq[i]);
            __sincosf(tk, &skv[i], &ckv[i]);
        }
    }

    // product-state amplitudes; idx bits (b3 b2 b1 b0) <-> qubits (0 1 2 3)
    const float pq01[4] = {cq[0]*cq[1], cq[0]*sq[1], sq[0]*cq[1], sq[0]*sq[1]};
    const float pq23[4] = {cq[2]*cq[3], cq[2]*sq[3], sq[2]*cq[3], sq[2]*sq[3]};
    const float pk01[4] = {ckv[0]*ckv[1], ckv[0]*skv[1], skv[0]*ckv[1], skv[0]*skv[1]};
    const float pk23[4] = {ckv[2]*ckv[3], ckv[2]*skv[3], skv[2]*ckv[3], skv[2]*skv[3]};

    float bk[16];
    #pragma unroll
    for (int j = 0; j < 16; ++j) bk[j] = pk01[j >> 2] * pk23[j & 3];

    float ovr = 0.0f, ovi = 0.0f;
    #pragma unroll
    for (int i = 0; i < 16; ++i) {
        float wr = 0.0f, wi = 0.0f;
        #pragma unroll
        for (int j = 0; j < 16; ++j) {
            const float2 g = Gs[i*16 + j];          // wave-uniform -> LDS broadcast
            wr = fmaf(g.x, bk[j], wr);
            wi = fmaf(g.y, bk[j], wi);
        }
        const float ai = pq01[i >> 2] * pq23[i & 3];
        ovr = fmaf(ai, wr, ovr);
        ovi = fmaf(ai, wi, ovi);
    }

    out[b] = fmaf(0.5f, ovr*ovr + ovi*ovi, 0.5f);
}

extern "C" void kernel_launch(void* const* d_in, const int* in_sizes, int n_in,
                              void* d_out, int out_size, void* d_ws, size_t ws_size,
                              hipStream_t stream) {
    const float* query = (const float*)d_in[0];
    const float* key   = (const float*)d_in[1];
    const float* Wq    = (const float*)d_in[2];
    const float* Wk    = (const float*)d_in[3];
    float* out = (float*)d_out;
    float2* G  = (float2*)d_ws;                     // 256 * 8 B = 2 KB scratch

    const int B = in_sizes[0] / 64;

    qdp_setup<<<1, 16, 0, stream>>>(Wq, Wk, G);
    qdp_main<<<(B + 255) / 256, 256, 0, stream>>>(query, key, G, out, B);
}

// Round 3
// 149.670 us; speedup vs baseline: 1.0827x; 1.0827x over previous
//
#include <hip/hip_runtime.h>

// ---------- complex helpers ----------
__device__ __forceinline__ float2 cmul(float2 a, float2 b) {
    return make_float2(a.x*b.x - a.y*b.y, a.x*b.y + a.y*b.x);
}
__device__ __forceinline__ float2 cfma(float2 a, float2 b, float2 acc) {
    acc.x = fmaf(a.x, b.x, fmaf(-a.y, b.y, acc.x));
    acc.y = fmaf(a.x, b.y, fmaf( a.y, b.x, acc.y));
    return acc;
}
// acc += conj(a) * b
__device__ __forceinline__ float2 cfma_conj(float2 a, float2 b, float2 acc) {
    acc.x = fmaf(a.x, b.x, fmaf( a.y, b.y, acc.x));
    acc.y = fmaf(a.x, b.y, fmaf(-a.y, b.x, acc.y));
    return acc;
}

// ---------- kernel 1: build G = Mq^dagger * Mk (16x16 complex) ----------
// 16 threads; thread t owns column t of Mq and Mk in registers.
// All trig via hardware v_sin/v_cos (__sinf/__cosf): angles are |W|~0.1,
// hw error ~1e-6 << 2e-2 threshold. No libcalls, no scratch.
__global__ void qdp_setup(const float* __restrict__ Wq,
                          const float* __restrict__ Wk,
                          float2* __restrict__ G) {
    const int t = threadIdx.x;            // 0..15 = column index
    float2 cq[16], ck[16];
    #pragma unroll
    for (int x = 0; x < 16; ++x) {
        cq[x] = make_float2(x == t ? 1.0f : 0.0f, 0.0f);
        ck[x] = cq[x];
    }

    #pragma unroll
    for (int layer = 0; layer < 2; ++layer) {
        #pragma unroll
        for (int w = 0; w < 4; ++w) {
            const int mask = 1 << (3 - w);          // wire w <-> bit (3-w)
            #pragma unroll
            for (int which = 0; which < 2; ++which) {
                const float* wp = (which ? Wk : Wq) + layer*12 + w*3;
                float2* col = which ? ck : cq;
                const float phi = wp[0], th = wp[1], om = wp[2];
                const float ht = 0.5f*th, ap = 0.5f*(phi+om), am = 0.5f*(phi-om);
                const float c   = __cosf(ht),  s   = __sinf(ht);
                const float cap = __cosf(ap),  sap = __sinf(ap);
                const float cam = __cosf(am),  sam = __sinf(am);
                const float2 u00 = make_float2( c*cap, -c*sap);
                const float2 u01 = make_float2(-s*cam, -s*sam);
                const float2 u10 = make_float2( s*cam, -s*sam);
                const float2 u11 = make_float2( c*cap,  c*sap);
                #pragma unroll
                for (int x = 0; x < 16; ++x) {
                    if (x & mask) continue;
                    const int y = x | mask;
                    const float2 a = col[x], b = col[y];
                    float2 nx = cmul(u00, a); nx = cfma(u01, b, nx);
                    float2 ny = cmul(u10, a); ny = cfma(u11, b, ny);
                    col[x] = nx; col[y] = ny;
                }
            }
        }
        #pragma unroll
        for (int w = 0; w < 3; ++w) {               // CNOT(w, w+1)
            const int mc = 1 << (3 - w);            // control bit
            const int mt = 1 << (2 - w);            // target bit
            #pragma unroll
            for (int x = 0; x < 16; ++x) {
                if ((x & mc) && !(x & mt)) {
                    const int y = x | mt;
                    float2 tmp = cq[x]; cq[x] = cq[y]; cq[y] = tmp;
                    tmp = ck[x]; ck[x] = ck[y]; ck[y] = tmp;
                }
            }
        }
    }

    __shared__ float2 MqL[16][16];                  // [row][col]
    #pragma unroll
    for (int kx = 0; kx < 16; ++kx) MqL[kx][t] = cq[kx];
    __syncthreads();

    // G[i][t] = sum_k conj(Mq[k][i]) * Mk[k][t]
    #pragma unroll
    for (int i = 0; i < 16; ++i) {
        float2 acc = make_float2(0.0f, 0.0f);
        #pragma unroll
        for (int kx = 0; kx < 16; ++kx)
            acc = cfma_conj(MqL[kx][i], ck[kx], acc);
        G[i*16 + t] = acc;
    }
}

// ---------- kernel 2: per-element bilinear form ----------
__device__ __forceinline__ float fast_tanh(float x) {
    const float e = __expf(2.0f * x);
    return 1.0f - 2.0f / (e + 1.0f);
}

__global__ __launch_bounds__(256)
void qdp_main(const float* __restrict__ Q, const float* __restrict__ K,
              const float2* __restrict__ G, float* __restrict__ out, int B) {
    __shared__ float2 Gs[256];
    Gs[threadIdx.x] = G[threadIdx.x];               // 256 threads, 256 entries
    __syncthreads();

    const int b = blockIdx.x * 256 + threadIdx.x;
    if (b >= B) return;

    const float4 qv = *reinterpret_cast<const float4*>(Q + (size_t)b * 64);
    const float4 kv = *reinterpret_cast<const float4*>(K + (size_t)b * 64);

    float cq[4], sq[4], ckv[4], skv[4];
    {
        const float qa[4] = {qv.x, qv.y, qv.z, qv.w};
        const float ka[4] = {kv.x, kv.y, kv.z, kv.w};
        #pragma unroll
        for (int i = 0; i < 4; ++i) {
            const float tq = fast_tanh(qa[i]) * 1.57079632679489662f;
            const float tk = fast_tanh(ka[i]) * 1.57079632679489662f;
            __sincosf(tq, &sq[i], &cq[i]);
            __sincosf(tk, &skv[i], &ckv[i]);
        }
    }

    // product-state amplitudes; idx bits (b3 b2 b1 b0) <-> qubits (0 1 2 3)
    const float pq01[4] = {cq[0]*cq[1], cq[0]*sq[1], sq[0]*cq[1], sq[0]*sq[1]};
    const float pq23[4] = {cq[2]*cq[3], cq[2]*sq[3], sq[2]*cq[3], sq[2]*sq[3]};
    const float pk01[4] = {ckv[0]*ckv[1], ckv[0]*skv[1], skv[0]*ckv[1], skv[0]*skv[1]};
    const float pk23[4] = {ckv[2]*ckv[3], ckv[2]*skv[3], skv[2]*ckv[3], skv[2]*skv[3]};

    float bk[16];
    #pragma unroll
    for (int j = 0; j < 16; ++j) bk[j] = pk01[j >> 2] * pk23[j & 3];

    float ovr = 0.0f, ovi = 0.0f;
    #pragma unroll
    for (int i = 0; i < 16; ++i) {
        float wr = 0.0f, wi = 0.0f;
        #pragma unroll
        for (int j = 0; j < 16; ++j) {
            const float2 g = Gs[i*16 + j];          // wave-uniform -> LDS broadcast
            wr = fmaf(g.x, bk[j], wr);
            wi = fmaf(g.y, bk[j], wi);
        }
        const float ai = pq01[i >> 2] * pq23[i & 3];
        ovr = fmaf(ai, wr, ovr);
        ovi = fmaf(ai, wi, ovi);
    }

    out[b] = fmaf(0.5f, ovr*ovr + ovi*ovi, 0.5f);
}

extern "C" void kernel_launch(void* const* d_in, const int* in_sizes, int n_in,
                              void* d_out, int out_size, void* d_ws, size_t ws_size,
                              hipStream_t stream) {
    const float* query = (const float*)d_in[0];
    const float* key   = (const float*)d_in[1];
    const float* Wq    = (const float*)d_in[2];
    const float* Wk    = (const float*)d_in[3];
    float* out = (float*)d_out;
    float2* G  = (float2*)d_ws;                     // 256 * 8 B = 2 KB scratch

    const int B = in_sizes[0] / 64;

    qdp_setup<<<1, 16, 0, stream>>>(Wq, Wk, G);
    qdp_main<<<(B + 255) / 256, 256, 0, stream>>>(query, key, G, out, B);
}

// Round 4
// 145.040 us; speedup vs baseline: 1.1172x; 1.0319x over previous
//
#include <hip/hip_runtime.h>

// ---------- complex helpers ----------
__device__ __forceinline__ float2 cmul(float2 a, float2 b) {
    return make_float2(a.x*b.x - a.y*b.y, a.x*b.y + a.y*b.x);
}
__device__ __forceinline__ float2 cfma(float2 a, float2 b, float2 acc) {
    acc.x = fmaf(a.x, b.x, fmaf(-a.y, b.y, acc.x));
    acc.y = fmaf(a.x, b.y, fmaf( a.y, b.x, acc.y));
    return acc;
}
// acc += conj(a) * b
__device__ __forceinline__ float2 cfma_conj(float2 a, float2 b, float2 acc) {
    acc.x = fmaf(a.x, b.x, fmaf( a.y, b.y, acc.x));
    acc.y = fmaf(a.x, b.y, fmaf(-a.y, b.x, acc.y));
    return acc;
}

__device__ __forceinline__ float fast_tanh(float x) {
    const float e = __expf(2.0f * x);
    return 1.0f - 2.0f / (e + 1.0f);
}

// ---------- fused kernel ----------
// Phase 1: threads 0..15 of each block redundantly build G = Mq^dagger Mk
//          (16x16 complex) into LDS. 48 hw-sincos + ~2 kFLOP per block,
//          Wq/Wk broadcast from L2 -> ~1-2 us latency, amortized across
//          1024 concurrent blocks.
// Phase 2: all 256 threads compute their element's bilinear form.
__global__ __launch_bounds__(256)
void qdp_fused(const float* __restrict__ Q, const float* __restrict__ K,
               const float* __restrict__ Wq, const float* __restrict__ Wk,
               float* __restrict__ out, int B) {
    __shared__ float2 Gs[256];
    __shared__ float2 MqL[16][16];                  // [row][col]

    const int t = threadIdx.x;

    float2 ck[16];
    if (t < 16) {
        float2 cq[16];
        #pragma unroll
        for (int x = 0; x < 16; ++x) {
            cq[x] = make_float2(x == t ? 1.0f : 0.0f, 0.0f);
            ck[x] = cq[x];
        }

        #pragma unroll
        for (int layer = 0; layer < 2; ++layer) {
            #pragma unroll
            for (int w = 0; w < 4; ++w) {
                const int mask = 1 << (3 - w);      // wire w <-> bit (3-w)
                #pragma unroll
                for (int which = 0; which < 2; ++which) {
                    const float* wp = (which ? Wk : Wq) + layer*12 + w*3;
                    float2* col = which ? ck : cq;
                    const float phi = wp[0], th = wp[1], om = wp[2];
                    const float ht = 0.5f*th, ap = 0.5f*(phi+om), am = 0.5f*(phi-om);
                    const float c   = __cosf(ht),  s   = __sinf(ht);
                    const float cap = __cosf(ap),  sap = __sinf(ap);
                    const float cam = __cosf(am),  sam = __sinf(am);
                    const float2 u00 = make_float2( c*cap, -c*sap);
                    const float2 u01 = make_float2(-s*cam, -s*sam);
                    const float2 u10 = make_float2( s*cam, -s*sam);
                    const float2 u11 = make_float2( c*cap,  c*sap);
                    #pragma unroll
                    for (int x = 0; x < 16; ++x) {
                        if (x & mask) continue;
                        const int y = x | mask;
                        const float2 a = col[x], b = col[y];
                        float2 nx = cmul(u00, a); nx = cfma(u01, b, nx);
                        float2 ny = cmul(u10, a); ny = cfma(u11, b, ny);
                        col[x] = nx; col[y] = ny;
                    }
                }
            }
            #pragma unroll
            for (int w = 0; w < 3; ++w) {           // CNOT(w, w+1)
                const int mc = 1 << (3 - w);        // control bit
                const int mt = 1 << (2 - w);        // target bit
                #pragma unroll
                for (int x = 0; x < 16; ++x) {
                    if ((x & mc) && !(x & mt)) {
                        const int y = x | mt;
                        float2 tmp = cq[x]; cq[x] = cq[y]; cq[y] = tmp;
                        tmp = ck[x]; ck[x] = ck[y]; ck[y] = tmp;
                    }
                }
            }
        }
        #pragma unroll
        for (int kx = 0; kx < 16; ++kx) MqL[kx][t] = cq[kx];
    }
    __syncthreads();

    if (t < 16) {
        // G[i][t] = sum_k conj(Mq[k][i]) * Mk[k][t]
        #pragma unroll
        for (int i = 0; i < 16; ++i) {
            float2 acc = make_float2(0.0f, 0.0f);
            #pragma unroll
            for (int kx = 0; kx < 16; ++kx)
                acc = cfma_conj(MqL[kx][i], ck[kx], acc);
            Gs[i*16 + t] = acc;
        }
    }
    __syncthreads();

    const int b = blockIdx.x * 256 + t;
    if (b >= B) return;                              // B % 256 == 0 here, no barriers below

    const float4 qv = *reinterpret_cast<const float4*>(Q + (size_t)b * 64);
    const float4 kv = *reinterpret_cast<const float4*>(K + (size_t)b * 64);

    float cqa[4], sqa[4], cka[4], ska[4];
    {
        const float qa[4] = {qv.x, qv.y, qv.z, qv.w};
        const float ka[4] = {kv.x, kv.y, kv.z, kv.w};
        #pragma unroll
        for (int i = 0; i < 4; ++i) {
            const float tq = fast_tanh(qa[i]) * 1.57079632679489662f;
            const float tk = fast_tanh(ka[i]) * 1.57079632679489662f;
            __sincosf(tq, &sqa[i], &cqa[i]);
            __sincosf(tk, &ska[i], &cka[i]);
        }
    }

    // product-state amplitudes; idx bits (b3 b2 b1 b0) <-> qubits (0 1 2 3)
    const float pq01[4] = {cqa[0]*cqa[1], cqa[0]*sqa[1], sqa[0]*cqa[1], sqa[0]*sqa[1]};
    const float pq23[4] = {cqa[2]*cqa[3], cqa[2]*sqa[3], sqa[2]*cqa[3], sqa[2]*sqa[3]};
    const float pk01[4] = {cka[0]*cka[1], cka[0]*ska[1], ska[0]*cka[1], ska[0]*ska[1]};
    const float pk23[4] = {cka[2]*cka[3], cka[2]*ska[3], ska[2]*cka[3], ska[2]*ska[3]};

    float bk[16];
    #pragma unroll
    for (int j = 0; j < 16; ++j) bk[j] = pk01[j >> 2] * pk23[j & 3];

    float ovr = 0.0f, ovi = 0.0f;
    #pragma unroll
    for (int i = 0; i < 16; ++i) {
        float wr = 0.0f, wi = 0.0f;
        #pragma unroll
        for (int j = 0; j < 16; ++j) {
            const float2 g = Gs[i*16 + j];          // wave-uniform -> LDS broadcast
            wr = fmaf(g.x, bk[j], wr);
            wi = fmaf(g.y, bk[j], wi);
        }
        const float ai = pq01[i >> 2] * pq23[i & 3];
        ovr = fmaf(ai, wr, ovr);
        ovi = fmaf(ai, wi, ovi);
    }

    out[b] = fmaf(0.5f, ovr*ovr + ovi*ovi, 0.5f);
}

extern "C" void kernel_launch(void* const* d_in, const int* in_sizes, int n_in,
                              void* d_out, int out_size, void* d_ws, size_t ws_size,
                              hipStream_t stream) {
    const float* query = (const float*)d_in[0];
    const float* key   = (const float*)d_in[1];
    const float* Wq    = (const float*)d_in[2];
    const float* Wk    = (const float*)d_in[3];
    float* out = (float*)d_out;

    const int B = in_sizes[0] / 64;

    qdp_fused<<<(B + 255) / 256, 256, 0, stream>>>(query, key, Wq, Wk, out, B);
}